// Round 1
// baseline (568.440 us; speedup 1.0000x reference)
//
#include <hip/hip_runtime.h>
#include <hip/hip_bf16.h>
#include <math.h>

// Problem: B=2, S=1024, D_MODEL=3072, HEADS=24, HEAD_DIM=128
#define B_   2
#define S_   1024
#define DM_  3072
#define H_   24
#define HD_  128
#define BH_  (B_*H_)          // 48
#define MROWS (B_*S_)         // 2048
#define QSCALE 0.08838834764831845f   // 1/sqrt(128)

typedef __attribute__((ext_vector_type(8))) short short8;
typedef __attribute__((ext_vector_type(4))) float f32x4;

__device__ __forceinline__ unsigned short f2bf(float f) {
    union { float f; unsigned u; } v; v.f = f;
    unsigned r = v.u + 0x7fffu + ((v.u >> 16) & 1u);   // RNE
    return (unsigned short)(r >> 16);
}

// ---------------- fp32 -> bf16 conversion ----------------
__global__ __launch_bounds__(256) void cvt_bf16(const float* __restrict__ src,
                                                unsigned short* __restrict__ dst, int n4) {
    int i = blockIdx.x * 256 + threadIdx.x;
    if (i >= n4) return;
    float4 v = ((const float4*)src)[i];
    ushort4 o;
    o.x = f2bf(v.x); o.y = f2bf(v.y); o.z = f2bf(v.z); o.w = f2bf(v.w);
    ((ushort4*)dst)[i] = o;
}

// ---------------- GEMM: C[M,N] = A[M,K] * B[N,K]^T  (bf16 in, fp32 out) ----
// 128x128 tile, BK=64, 256 threads (4 waves, each 64x64), 16x16x32 bf16 MFMA.
__global__ __launch_bounds__(256) void gemm_bt(const unsigned short* __restrict__ A,
                                               const unsigned short* __restrict__ Bm,
                                               float* __restrict__ C,
                                               int Ndim, int K) {
    __shared__ __align__(16) unsigned short As[128][72];  // +8 pad: 2-way banks (free)
    __shared__ __align__(16) unsigned short Bs[128][72];
    const int t = threadIdx.x;
    const int m0 = blockIdx.y * 128, n0 = blockIdx.x * 128;
    const int w = t >> 6, lane = t & 63, quad = lane >> 4, ln = lane & 15;
    const int wm = (w >> 1) * 64, wn = (w & 1) * 64;
    f32x4 acc[4][4];
#pragma unroll
    for (int i = 0; i < 4; ++i)
#pragma unroll
        for (int j = 0; j < 4; ++j) acc[i][j] = (f32x4){0.f, 0.f, 0.f, 0.f};
    const int nkt = K >> 6;
    for (int kt = 0; kt < nkt; ++kt) {
        const int k0 = kt << 6;
#pragma unroll
        for (int c = 0; c < 4; ++c) {
            int i = c * 256 + t;
            int r = i >> 3, cg = (i & 7) << 3;
            *(uint4*)&As[r][cg] = *(const uint4*)&A[(long long)(m0 + r) * K + k0 + cg];
            *(uint4*)&Bs[r][cg] = *(const uint4*)&Bm[(long long)(n0 + r) * K + k0 + cg];
        }
        __syncthreads();
#pragma unroll
        for (int ks = 0; ks < 2; ++ks) {
            short8 a[4], b[4];
#pragma unroll
            for (int i = 0; i < 4; ++i)
                a[i] = *(const short8*)&As[wm + i * 16 + ln][ks * 32 + quad * 8];
#pragma unroll
            for (int j = 0; j < 4; ++j)
                b[j] = *(const short8*)&Bs[wn + j * 16 + ln][ks * 32 + quad * 8];
#pragma unroll
            for (int i = 0; i < 4; ++i)
#pragma unroll
                for (int j = 0; j < 4; ++j)
                    acc[i][j] = __builtin_amdgcn_mfma_f32_16x16x32_bf16(a[i], b[j], acc[i][j], 0, 0, 0);
        }
        __syncthreads();
    }
    // C/D layout: col = lane&15, row = quad*4 + reg
#pragma unroll
    for (int i = 0; i < 4; ++i) {
#pragma unroll
        for (int reg = 0; reg < 4; ++reg) {
            int row = m0 + wm + i * 16 + quad * 4 + reg;
            float* crow = C + (long long)row * Ndim + n0 + wn + ln;
#pragma unroll
            for (int j = 0; j < 4; ++j) crow[j * 16] = acc[i][j][reg];
        }
    }
}

// ---------------- RMSNorm + RoPE + layout shuffle ----------------
// qkvf: fp32 (B*S, 9216) = [q | k | v] per row. One wave per (b,s,h) head-row.
// Writes Qb,Kb as (B,H,S,D) bf16 (Q pre-scaled by 1/sqrt(128)); V as (B,H,D,S).
__global__ __launch_bounds__(256) void norm_rope(const float* __restrict__ qkvf,
                                                 const float* __restrict__ freqs,
                                                 const float* __restrict__ wqv,
                                                 const float* __restrict__ wkv,
                                                 unsigned short* __restrict__ Qb,
                                                 unsigned short* __restrict__ Kb,
                                                 unsigned short* __restrict__ Vtb) {
    const int w = threadIdx.x >> 6, t = threadIdx.x & 63;
    const int row = blockIdx.x * 4 + w;      // 0 .. B*S*H-1
    const int h = row % H_;
    const int bs = row / H_;
    const int s = bs % S_;
    const int b = bs / S_;
    const float* qrow = qkvf + (long long)bs * (3 * DM_) + h * HD_;
    float c1 = cosf(freqs[s * HD_ + t]),      s1 = sinf(freqs[s * HD_ + t]);
    float c2 = cosf(freqs[s * HD_ + t + 64]), s2 = sinf(freqs[s * HD_ + t + 64]);
    const long long qo = ((long long)(b * H_ + h) * S_ + s) * HD_;
    {   // Q
        float x1 = qrow[t], x2 = qrow[t + 64];
        float ss = x1 * x1 + x2 * x2;
#pragma unroll
        for (int off = 32; off; off >>= 1) ss += __shfl_xor(ss, off);
        float rr = rsqrtf(ss * (1.f / 128.f) + 1e-6f);
        float y1 = x1 * rr * wqv[t], y2 = x2 * rr * wqv[t + 64];
        Qb[qo + t]      = f2bf((y1 * c1 - y2 * s1) * QSCALE);
        Qb[qo + t + 64] = f2bf((y2 * c2 + y1 * s2) * QSCALE);
    }
    {   // K
        const float* krow = qrow + DM_;
        float x1 = krow[t], x2 = krow[t + 64];
        float ss = x1 * x1 + x2 * x2;
#pragma unroll
        for (int off = 32; off; off >>= 1) ss += __shfl_xor(ss, off);
        float rr = rsqrtf(ss * (1.f / 128.f) + 1e-6f);
        float y1 = x1 * rr * wkv[t], y2 = x2 * rr * wkv[t + 64];
        Kb[qo + t]      = f2bf(y1 * c1 - y2 * s1);
        Kb[qo + t + 64] = f2bf(y2 * c2 + y1 * s2);
    }
    {   // V (transposed store: (B,H,D,S))
        const float* vrow = qrow + 2 * DM_;
        long long vo = (long long)(b * H_ + h) * HD_;
        Vtb[(vo + t) * S_ + s]      = f2bf(vrow[t]);
        Vtb[(vo + t + 64) * S_ + s] = f2bf(vrow[t + 64]);
    }
}

// ---------------- Flash attention ----------------
// grid (BH=48, S/64=16). 4 waves/block, each wave owns 16 Q rows.
// Per K-tile (64 keys): QK^T via MFMA, online softmax (quad shfl reduce),
// P through LDS (C-layout -> A-layout), PV via MFMA. O accum fp32 in regs.
__global__ __launch_bounds__(256) void attn(const unsigned short* __restrict__ Qb,
                                            const unsigned short* __restrict__ Kb,
                                            const unsigned short* __restrict__ Vtb,
                                            unsigned short* __restrict__ Ob) {
    __shared__ __align__(16) unsigned short Ks[64][136];   // 64 keys x 128 d (+8 pad)
    __shared__ __align__(16) unsigned short Vts[128][72];  // 128 d x 64 keys (+8 pad)
    __shared__ __align__(16) unsigned short Ps[4][16][72]; // per-wave P 16x64 (+8 pad)
    const int bh = blockIdx.x, qt = blockIdx.y;
    const int t = threadIdx.x, w = t >> 6, lane = t & 63, quad = lane >> 4, ln = lane & 15;
    const int b = bh / H_, h = bh - b * H_;

    short8 qfrag[4];
    const long long qbase = ((long long)bh * S_ + qt * 64 + w * 16 + ln) * HD_;
#pragma unroll
    for (int ks = 0; ks < 4; ++ks)
        qfrag[ks] = *(const short8*)&Qb[qbase + ks * 32 + quad * 8];

    f32x4 o[8];
#pragma unroll
    for (int n = 0; n < 8; ++n) o[n] = (f32x4){0.f, 0.f, 0.f, 0.f};
    float m_run[4], l_run[4];
#pragma unroll
    for (int r = 0; r < 4; ++r) { m_run[r] = -1e30f; l_run[r] = 0.f; }

    for (int kt = 0; kt < S_ / 64; ++kt) {
        __syncthreads();
#pragma unroll
        for (int c = 0; c < 4; ++c) {
            int i = c * 256 + t;
            int r = i >> 4, cg = (i & 15) << 3;
            *(uint4*)&Ks[r][cg] = *(const uint4*)&Kb[((long long)bh * S_ + kt * 64 + r) * HD_ + cg];
            int r2 = i >> 3, cg2 = (i & 7) << 3;
            *(uint4*)&Vts[r2][cg2] = *(const uint4*)&Vtb[((long long)bh * HD_ + r2) * S_ + kt * 64 + cg2];
        }
        __syncthreads();
        // S = Q K^T  (4 subtiles of 16 keys)
        f32x4 sj[4];
#pragma unroll
        for (int j = 0; j < 4; ++j) {
            f32x4 sa = (f32x4){0.f, 0.f, 0.f, 0.f};
#pragma unroll
            for (int ks = 0; ks < 4; ++ks) {
                short8 bb = *(const short8*)&Ks[j * 16 + ln][ks * 32 + quad * 8];
                sa = __builtin_amdgcn_mfma_f32_16x16x32_bf16(qfrag[ks], bb, sa, 0, 0, 0);
            }
            sj[j] = sa;
        }
        // online softmax: rows live in a quad (row = quad*4+reg, cols across 16 lanes)
        float al[4];
#pragma unroll
        for (int r = 0; r < 4; ++r) {
            float m = fmaxf(fmaxf(sj[0][r], sj[1][r]), fmaxf(sj[2][r], sj[3][r]));
#pragma unroll
            for (int off = 8; off; off >>= 1) m = fmaxf(m, __shfl_xor(m, off, 16));
            float mn = fmaxf(m_run[r], m);
            al[r] = __expf(m_run[r] - mn);
            m_run[r] = mn;
            float sum = 0.f;
#pragma unroll
            for (int j = 0; j < 4; ++j) {
                float p = __expf(sj[j][r] - mn);
                sj[j][r] = p;
                sum += p;
            }
#pragma unroll
            for (int off = 8; off; off >>= 1) sum += __shfl_xor(sum, off, 16);
            l_run[r] = l_run[r] * al[r] + sum;
        }
#pragma unroll
        for (int n = 0; n < 8; ++n)
#pragma unroll
            for (int r = 0; r < 4; ++r) o[n][r] *= al[r];
        // P: C-layout -> LDS -> A-layout
#pragma unroll
        for (int j = 0; j < 4; ++j)
#pragma unroll
            for (int r = 0; r < 4; ++r)
                Ps[w][quad * 4 + r][j * 16 + ln] = f2bf(sj[j][r]);
        __asm__ volatile("s_waitcnt lgkmcnt(0)" ::: "memory");
        // O += P V
#pragma unroll
        for (int ks = 0; ks < 2; ++ks) {
            short8 pf = *(const short8*)&Ps[w][ln][ks * 32 + quad * 8];
#pragma unroll
            for (int n = 0; n < 8; ++n) {
                short8 vf = *(const short8*)&Vts[n * 16 + ln][ks * 32 + quad * 8];
                o[n] = __builtin_amdgcn_mfma_f32_16x16x32_bf16(pf, vf, o[n], 0, 0, 0);
            }
        }
    }
    float inv[4];
#pragma unroll
    for (int r = 0; r < 4; ++r) inv[r] = 1.f / l_run[r];
    const int row_s = qt * 64 + w * 16 + quad * 4;
#pragma unroll
    for (int n = 0; n < 8; ++n)
#pragma unroll
        for (int r = 0; r < 4; ++r) {
            long long off = ((long long)b * S_ + row_s + r) * DM_ + h * HD_ + n * 16 + ln;
            Ob[off] = f2bf(o[n][r] * inv[r]);
        }
}

// ---------------- host side ----------------
extern "C" void kernel_launch(void* const* d_in, const int* in_sizes, int n_in,
                              void* d_out, int out_size, void* d_ws, size_t ws_size,
                              hipStream_t stream) {
    const float* hs    = (const float*)d_in[0];
    const float* freqs = (const float*)d_in[1];
    const float* Wq    = (const float*)d_in[2];
    const float* Wk    = (const float*)d_in[3];
    const float* Wv    = (const float*)d_in[4];
    const float* Wo    = (const float*)d_in[5];
    const float* nqw   = (const float*)d_in[6];
    const float* nkw   = (const float*)d_in[7];
    float* out = (float*)d_out;

    char* ws = (char*)d_ws;
    // workspace layout (bytes)
    unsigned short* Xb    = (unsigned short*)(ws);                   // 12,582,912
    unsigned short* Wqkvb = (unsigned short*)(ws + 12582912LL);      // 56,623,104 (Wq|Wk|Wv)
    unsigned short* Wob   = (unsigned short*)(ws + 69206016LL);      // 18,874,368
    float*          qkvf  = (float*)        (ws + 88080384LL);       // 75,497,472 (2048 x 9216 fp32)
    unsigned short* Qb    = (unsigned short*)(ws + 163577856LL);     // 12,582,912 (B,H,S,D)
    unsigned short* Kb    = (unsigned short*)(ws + 176160768LL);     // 12,582,912 (B,H,S,D)
    unsigned short* Vtb   = (unsigned short*)(ws + 188743680LL);     // 12,582,912 (B,H,D,S)
    unsigned short* Ob    = (unsigned short*)(ws + 201326592LL);     // 12,582,912 (B,S,H*D)
    // total: 213,909,504 bytes

    // 1. convert inputs to bf16
    cvt_bf16<<<6144, 256, 0, stream>>>(hs, Xb, 1572864);
    cvt_bf16<<<9216, 256, 0, stream>>>(Wq, Wqkvb,            2359296);
    cvt_bf16<<<9216, 256, 0, stream>>>(Wk, Wqkvb +  9437184, 2359296);
    cvt_bf16<<<9216, 256, 0, stream>>>(Wv, Wqkvb + 18874368, 2359296);
    cvt_bf16<<<9216, 256, 0, stream>>>(Wo, Wob,              2359296);
    // 2. fused QKV projection: (2048 x 3072) x (9216 x 3072)^T -> fp32
    gemm_bt<<<dim3(72, 16), 256, 0, stream>>>(Xb, Wqkvb, qkvf, 3 * DM_, DM_);
    // 3. RMSNorm + RoPE + layout (one wave per head-row)
    norm_rope<<<(B_ * S_ * H_) / 4, 256, 0, stream>>>(qkvf, freqs, nqw, nkw, Qb, Kb, Vtb);
    // 4. flash attention
    attn<<<dim3(BH_, S_ / 64), 256, 0, stream>>>(Qb, Kb, Vtb, Ob);
    // 5. output projection: (2048 x 3072) x (3072 x 3072)^T -> d_out fp32
    gemm_bt<<<dim3(24, 16), 256, 0, stream>>>(Ob, Wob, out, DM_, DM_);
}

// Round 2
// 558.972 us; speedup vs baseline: 1.0169x; 1.0169x over previous
//
#include <hip/hip_runtime.h>
#include <hip/hip_bf16.h>
#include <math.h>

// Problem: B=2, S=1024, D_MODEL=3072, HEADS=24, HEAD_DIM=128
#define B_   2
#define S_   1024
#define DM_  3072
#define H_   24
#define HD_  128
#define BH_  (B_*H_)          // 48
#define MROWS (B_*S_)         // 2048
#define QSCALE 0.08838834764831845f   // 1/sqrt(128)

typedef __attribute__((ext_vector_type(8))) short short8;
typedef __attribute__((ext_vector_type(4))) float f32x4;

__device__ __forceinline__ unsigned short f2bf(float f) {
    union { float f; unsigned u; } v; v.f = f;
    unsigned r = v.u + 0x7fffu + ((v.u >> 16) & 1u);   // RNE
    return (unsigned short)(r >> 16);
}

// async 16B global -> LDS (wave-uniform lds base + lane*16)
#define GLD_LDS16(gptr, ldsptr)                                                            \
    __builtin_amdgcn_global_load_lds(                                                      \
        (const __attribute__((address_space(1))) unsigned int*)(gptr),                     \
        (__attribute__((address_space(3))) unsigned int*)(ldsptr), 16, 0, 0)

// ---------------- fp32 -> bf16 conversion ----------------
__global__ __launch_bounds__(256) void cvt_bf16(const float* __restrict__ src,
                                                unsigned short* __restrict__ dst, int n4) {
    int i = blockIdx.x * 256 + threadIdx.x;
    if (i >= n4) return;
    float4 v = ((const float4*)src)[i];
    ushort4 o;
    o.x = f2bf(v.x); o.y = f2bf(v.y); o.z = f2bf(v.z); o.w = f2bf(v.w);
    ((ushort4*)dst)[i] = o;
}

// ---------------- rope cos/sin table ----------------
__global__ __launch_bounds__(256) void rope_tab(const float* __restrict__ freqs,
                                                float2* __restrict__ tab) {
    int i = blockIdx.x * 256 + threadIdx.x;   // S_*HD_ elements
    float f = freqs[i];
    tab[i] = make_float2(cosf(f), sinf(f));
}

// ---------------- GEMM: C[M,N] = A[M,K] * B[N,K]^T  (bf16 in, fp32 out) ----
// 128x128 tile, BK=64, 256 threads (4 waves, each 64x64), 16x16x32 bf16 MFMA.
// Staging via global_load_lds width=16; XOR-swizzled LDS chunks:
//   LDS chunk c of row r holds global k-chunk (c ^ (r&7)); read side un-swizzles.
__global__ __launch_bounds__(256) void gemm_bt(const unsigned short* __restrict__ A,
                                               const unsigned short* __restrict__ Bm,
                                               float* __restrict__ C,
                                               int Ndim, int K) {
    __shared__ __align__(16) unsigned short As[128 * 64];  // unpadded (global_load_lds)
    __shared__ __align__(16) unsigned short Bs[128 * 64];
    const int t = threadIdx.x;
    const int m0 = blockIdx.y * 128, n0 = blockIdx.x * 128;
    const int w = t >> 6, lane = t & 63, quad = lane >> 4, ln = lane & 15;
    const int wm = (w >> 1) * 64, wn = (w & 1) * 64;
    // staging lane roles: 8 rows x 8 chunks per wave-instruction
    const int rl = lane >> 3;             // row within 8-row group
    const int gc = (lane & 7) ^ rl;       // swizzled global chunk this lane fetches
    const int cs = ln & 7;                // read-side swizzle key (row&7)

    f32x4 acc[4][4];
#pragma unroll
    for (int i = 0; i < 4; ++i)
#pragma unroll
        for (int j = 0; j < 4; ++j) acc[i][j] = (f32x4){0.f, 0.f, 0.f, 0.f};

    // per-lane global base addresses for staging (advance by 64 shorts each kt)
    const unsigned short* ga = &A[(long long)(m0 + w * 32 + rl) * K + gc * 8];
    const unsigned short* gb = &Bm[(long long)(n0 + w * 32 + rl) * K + gc * 8];

    const int nkt = K >> 6;
    for (int kt = 0; kt < nkt; ++kt) {
#pragma unroll
        for (int c = 0; c < 4; ++c) {
            const int r0 = w * 32 + c * 8;
            GLD_LDS16(ga + (long long)(c * 8) * K, &As[r0 * 64]);
            GLD_LDS16(gb + (long long)(c * 8) * K, &Bs[r0 * 64]);
        }
        ga += 64; gb += 64;
        __syncthreads();
#pragma unroll
        for (int ks = 0; ks < 2; ++ks) {
            short8 a[4], b[4];
#pragma unroll
            for (int i = 0; i < 4; ++i) {
                int row = wm + i * 16 + ln;
                a[i] = *(const short8*)&As[row * 64 + (((ks * 4 + quad) ^ cs) << 3)];
            }
#pragma unroll
            for (int j = 0; j < 4; ++j) {
                int row = wn + j * 16 + ln;
                b[j] = *(const short8*)&Bs[row * 64 + (((ks * 4 + quad) ^ cs) << 3)];
            }
#pragma unroll
            for (int i = 0; i < 4; ++i)
#pragma unroll
                for (int j = 0; j < 4; ++j)
                    acc[i][j] = __builtin_amdgcn_mfma_f32_16x16x32_bf16(a[i], b[j], acc[i][j], 0, 0, 0);
        }
        __syncthreads();
    }
    // C/D layout: col = lane&15, row = quad*4 + reg
#pragma unroll
    for (int i = 0; i < 4; ++i) {
#pragma unroll
        for (int reg = 0; reg < 4; ++reg) {
            int row = m0 + wm + i * 16 + quad * 4 + reg;
            float* crow = C + (long long)row * Ndim + n0 + wn + ln;
#pragma unroll
            for (int j = 0; j < 4; ++j) crow[j * 16] = acc[i][j][reg];
        }
    }
}

// ---------------- RMSNorm + RoPE + layout shuffle ----------------
// qkvf: fp32 (B*S, 9216) = [q | k | v] per row. One wave per (b,s,h) head-row.
// Writes Qb,Kb as (B,H,S,D) bf16 (Q pre-scaled by 1/sqrt(128)); V as (B,H,D,S).
__global__ __launch_bounds__(256) void norm_rope(const float* __restrict__ qkvf,
                                                 const float2* __restrict__ tab,
                                                 const float* __restrict__ wqv,
                                                 const float* __restrict__ wkv,
                                                 unsigned short* __restrict__ Qb,
                                                 unsigned short* __restrict__ Kb,
                                                 unsigned short* __restrict__ Vtb) {
    const int w = threadIdx.x >> 6, t = threadIdx.x & 63;
    const int row = blockIdx.x * 4 + w;      // 0 .. B*S*H-1
    const int h = row % H_;
    const int bs = row / H_;
    const int s = bs % S_;
    const int b = bs / S_;
    const float* qrow = qkvf + (long long)bs * (3 * DM_) + h * HD_;
    float2 cs1 = tab[s * HD_ + t];
    float2 cs2 = tab[s * HD_ + t + 64];
    const long long qo = ((long long)(b * H_ + h) * S_ + s) * HD_;
    {   // Q
        float x1 = qrow[t], x2 = qrow[t + 64];
        float ss = x1 * x1 + x2 * x2;
#pragma unroll
        for (int off = 32; off; off >>= 1) ss += __shfl_xor(ss, off);
        float rr = rsqrtf(ss * (1.f / 128.f) + 1e-6f);
        float y1 = x1 * rr * wqv[t], y2 = x2 * rr * wqv[t + 64];
        Qb[qo + t]      = f2bf((y1 * cs1.x - y2 * cs1.y) * QSCALE);
        Qb[qo + t + 64] = f2bf((y2 * cs2.x + y1 * cs2.y) * QSCALE);
    }
    {   // K
        const float* krow = qrow + DM_;
        float x1 = krow[t], x2 = krow[t + 64];
        float ss = x1 * x1 + x2 * x2;
#pragma unroll
        for (int off = 32; off; off >>= 1) ss += __shfl_xor(ss, off);
        float rr = rsqrtf(ss * (1.f / 128.f) + 1e-6f);
        float y1 = x1 * rr * wkv[t], y2 = x2 * rr * wkv[t + 64];
        Kb[qo + t]      = f2bf(y1 * cs1.x - y2 * cs1.y);
        Kb[qo + t + 64] = f2bf(y2 * cs2.x + y1 * cs2.y);
    }
    {   // V (transposed store: (B,H,D,S))
        const float* vrow = qrow + 2 * DM_;
        long long vo = (long long)(b * H_ + h) * HD_;
        Vtb[(vo + t) * S_ + s]      = f2bf(vrow[t]);
        Vtb[(vo + t + 64) * S_ + s] = f2bf(vrow[t + 64]);
    }
}

// ---------------- Flash attention ----------------
// grid (BH=48, S/64=16). 4 waves/block, each wave owns 16 Q rows.
__global__ __launch_bounds__(256) void attn(const unsigned short* __restrict__ Qb,
                                            const unsigned short* __restrict__ Kb,
                                            const unsigned short* __restrict__ Vtb,
                                            unsigned short* __restrict__ Ob) {
    __shared__ __align__(16) unsigned short Ks[64][136];   // 64 keys x 128 d (+8 pad)
    __shared__ __align__(16) unsigned short Vts[128][72];  // 128 d x 64 keys (+8 pad)
    __shared__ __align__(16) unsigned short Ps[4][16][72]; // per-wave P 16x64 (+8 pad)
    const int bh = blockIdx.x, qt = blockIdx.y;
    const int t = threadIdx.x, w = t >> 6, lane = t & 63, quad = lane >> 4, ln = lane & 15;
    const int b = bh / H_, h = bh - b * H_;

    short8 qfrag[4];
    const long long qbase = ((long long)bh * S_ + qt * 64 + w * 16 + ln) * HD_;
#pragma unroll
    for (int ks = 0; ks < 4; ++ks)
        qfrag[ks] = *(const short8*)&Qb[qbase + ks * 32 + quad * 8];

    f32x4 o[8];
#pragma unroll
    for (int n = 0; n < 8; ++n) o[n] = (f32x4){0.f, 0.f, 0.f, 0.f};
    float m_run[4], l_run[4];
#pragma unroll
    for (int r = 0; r < 4; ++r) { m_run[r] = -1e30f; l_run[r] = 0.f; }

    for (int kt = 0; kt < S_ / 64; ++kt) {
        __syncthreads();
#pragma unroll
        for (int c = 0; c < 4; ++c) {
            int i = c * 256 + t;
            int r = i >> 4, cg = (i & 15) << 3;
            *(uint4*)&Ks[r][cg] = *(const uint4*)&Kb[((long long)bh * S_ + kt * 64 + r) * HD_ + cg];
            int r2 = i >> 3, cg2 = (i & 7) << 3;
            *(uint4*)&Vts[r2][cg2] = *(const uint4*)&Vtb[((long long)bh * HD_ + r2) * S_ + kt * 64 + cg2];
        }
        __syncthreads();
        // S = Q K^T  (4 subtiles of 16 keys)
        f32x4 sj[4];
#pragma unroll
        for (int j = 0; j < 4; ++j) {
            f32x4 sa = (f32x4){0.f, 0.f, 0.f, 0.f};
#pragma unroll
            for (int ks = 0; ks < 4; ++ks) {
                short8 bb = *(const short8*)&Ks[j * 16 + ln][ks * 32 + quad * 8];
                sa = __builtin_amdgcn_mfma_f32_16x16x32_bf16(qfrag[ks], bb, sa, 0, 0, 0);
            }
            sj[j] = sa;
        }
        // online softmax: rows live in a quad (row = quad*4+reg, cols across 16 lanes)
        float al[4];
#pragma unroll
        for (int r = 0; r < 4; ++r) {
            float m = fmaxf(fmaxf(sj[0][r], sj[1][r]), fmaxf(sj[2][r], sj[3][r]));
#pragma unroll
            for (int off = 8; off; off >>= 1) m = fmaxf(m, __shfl_xor(m, off, 16));
            float mn = fmaxf(m_run[r], m);
            al[r] = __expf(m_run[r] - mn);
            m_run[r] = mn;
            float sum = 0.f;
#pragma unroll
            for (int j = 0; j < 4; ++j) {
                float p = __expf(sj[j][r] - mn);
                sj[j][r] = p;
                sum += p;
            }
#pragma unroll
            for (int off = 8; off; off >>= 1) sum += __shfl_xor(sum, off, 16);
            l_run[r] = l_run[r] * al[r] + sum;
        }
#pragma unroll
        for (int n = 0; n < 8; ++n)
#pragma unroll
            for (int r = 0; r < 4; ++r) o[n][r] *= al[r];
        // P: C-layout -> LDS -> A-layout
#pragma unroll
        for (int j = 0; j < 4; ++j)
#pragma unroll
            for (int r = 0; r < 4; ++r)
                Ps[w][quad * 4 + r][j * 16 + ln] = f2bf(sj[j][r]);
        __asm__ volatile("s_waitcnt lgkmcnt(0)" ::: "memory");
        // O += P V
#pragma unroll
        for (int ks = 0; ks < 2; ++ks) {
            short8 pf = *(const short8*)&Ps[w][ln][ks * 32 + quad * 8];
#pragma unroll
            for (int n = 0; n < 8; ++n) {
                short8 vf = *(const short8*)&Vts[n * 16 + ln][ks * 32 + quad * 8];
                o[n] = __builtin_amdgcn_mfma_f32_16x16x32_bf16(pf, vf, o[n], 0, 0, 0);
            }
        }
    }
    float inv[4];
#pragma unroll
    for (int r = 0; r < 4; ++r) inv[r] = 1.f / l_run[r];
    const int row_s = qt * 64 + w * 16 + quad * 4;
#pragma unroll
    for (int n = 0; n < 8; ++n)
#pragma unroll
        for (int r = 0; r < 4; ++r) {
            long long off = ((long long)b * S_ + row_s + r) * DM_ + h * HD_ + n * 16 + ln;
            Ob[off] = f2bf(o[n][r] * inv[r]);
        }
}

// ---------------- host side ----------------
extern "C" void kernel_launch(void* const* d_in, const int* in_sizes, int n_in,
                              void* d_out, int out_size, void* d_ws, size_t ws_size,
                              hipStream_t stream) {
    const float* hs    = (const float*)d_in[0];
    const float* freqs = (const float*)d_in[1];
    const float* Wq    = (const float*)d_in[2];
    const float* Wk    = (const float*)d_in[3];
    const float* Wv    = (const float*)d_in[4];
    const float* Wo    = (const float*)d_in[5];
    const float* nqw   = (const float*)d_in[6];
    const float* nkw   = (const float*)d_in[7];
    float* out = (float*)d_out;

    char* ws = (char*)d_ws;
    // workspace layout (bytes)
    unsigned short* Xb    = (unsigned short*)(ws);                   // 12,582,912
    unsigned short* Wqkvb = (unsigned short*)(ws + 12582912LL);      // 56,623,104 (Wq|Wk|Wv)
    unsigned short* Wob   = (unsigned short*)(ws + 69206016LL);      // 18,874,368
    float*          qkvf  = (float*)        (ws + 88080384LL);       // 75,497,472 (2048 x 9216 fp32)
    unsigned short* Qb    = (unsigned short*)(ws + 163577856LL);     // 12,582,912 (B,H,S,D)
    unsigned short* Kb    = (unsigned short*)(ws + 176160768LL);     // 12,582,912 (B,H,S,D)
    unsigned short* Vtb   = (unsigned short*)(ws + 188743680LL);     // 12,582,912 (B,H,D,S)
    unsigned short* Ob    = (unsigned short*)(ws + 201326592LL);     // 12,582,912 (B,S,H*D)
    float2*         rtab  = (float2*)        (ws + 213909504LL);     // 1,048,576
    // total: 214,958,080 bytes

    // 1. convert inputs to bf16 + rope table
    cvt_bf16<<<6144, 256, 0, stream>>>(hs, Xb, 1572864);
    cvt_bf16<<<9216, 256, 0, stream>>>(Wq, Wqkvb,            2359296);
    cvt_bf16<<<9216, 256, 0, stream>>>(Wk, Wqkvb +  9437184, 2359296);
    cvt_bf16<<<9216, 256, 0, stream>>>(Wv, Wqkvb + 18874368, 2359296);
    cvt_bf16<<<9216, 256, 0, stream>>>(Wo, Wob,              2359296);
    rope_tab<<<512, 256, 0, stream>>>(freqs, rtab);
    // 2. fused QKV projection: (2048 x 3072) x (9216 x 3072)^T -> fp32
    gemm_bt<<<dim3(72, 16), 256, 0, stream>>>(Xb, Wqkvb, qkvf, 3 * DM_, DM_);
    // 3. RMSNorm + RoPE + layout (one wave per head-row)
    norm_rope<<<(B_ * S_ * H_) / 4, 256, 0, stream>>>(qkvf, rtab, nqw, nkw, Qb, Kb, Vtb);
    // 4. flash attention
    attn<<<dim3(BH_, S_ / 64), 256, 0, stream>>>(Qb, Kb, Vtb, Ob);
    // 5. output projection: (2048 x 3072) x (3072 x 3072)^T -> d_out fp32
    gemm_bt<<<dim3(24, 16), 256, 0, stream>>>(Ob, Wob, out, DM_, DM_);
}

// Round 3
// 508.535 us; speedup vs baseline: 1.1178x; 1.0992x over previous
//
#include <hip/hip_runtime.h>
#include <hip/hip_bf16.h>
#include <math.h>

// Problem: B=2, S=1024, D_MODEL=3072, HEADS=24, HEAD_DIM=128
#define B_   2
#define S_   1024
#define DM_  3072
#define H_   24
#define HD_  128
#define BH_  (B_*H_)          // 48
#define KDIM 3072             // K of both GEMMs
#define QSCALE 0.08838834764831845f   // 1/sqrt(128)

typedef __attribute__((ext_vector_type(8))) short short8;
typedef __attribute__((ext_vector_type(4))) float f32x4;

__device__ __forceinline__ unsigned short f2bf(float f) {
    union { float f; unsigned u; } v; v.f = f;
    unsigned r = v.u + 0x7fffu + ((v.u >> 16) & 1u);   // RNE
    return (unsigned short)(r >> 16);
}

// async 16B global -> LDS (wave-uniform lds base + lane*16)
#define GLD_LDS16(gptr, ldsptr)                                                            \
    __builtin_amdgcn_global_load_lds(                                                      \
        (const __attribute__((address_space(1))) unsigned int*)(gptr),                     \
        (__attribute__((address_space(3))) unsigned int*)(ldsptr), 16, 0, 0)

// ---------------- fp32 -> bf16 conversion ----------------
__global__ __launch_bounds__(256) void cvt_bf16(const float* __restrict__ src,
                                                unsigned short* __restrict__ dst, int n4) {
    int i = blockIdx.x * 256 + threadIdx.x;
    if (i >= n4) return;
    float4 v = ((const float4*)src)[i];
    ushort4 o;
    o.x = f2bf(v.x); o.y = f2bf(v.y); o.z = f2bf(v.z); o.w = f2bf(v.w);
    ((ushort4*)dst)[i] = o;
}

// ---------------- rope cos/sin table ----------------
__global__ __launch_bounds__(256) void rope_tab(const float* __restrict__ freqs,
                                                float2* __restrict__ tab) {
    int i = blockIdx.x * 256 + threadIdx.x;   // S_*HD_ elements
    float f = freqs[i];
    tab[i] = make_float2(cosf(f), sinf(f));
}

// ---------------- GEMM: C[M,N] = A[M,K] * B[N,K]^T  (bf16 in) ----------------
// 128x128 tile, BK=64, 256 threads (4 waves, 64x64 each), 16x16x32 bf16 MFMA.
// Staging via global_load_lds width=16 with XOR chunk swizzle (conflict-free).
// B rows are PERMUTED at staging so that wave p=w&1 holds global cols
//   p=0: {0-31, 64-95}, p=1: {32-63, 96-127}  (fragment col = dj0+(j&1)*16+(j>>1)*64+ln)
// -> each RoPE pair (d, d+64) lives in one lane (j and j+2).
// FUSED=1: N=9216 QKV projection; epilogue does RMSNorm+RoPE and writes
//   Qb,Kb (B,H,S,D bf16; Q pre-scaled 1/sqrt(128)) and Vtb (B,H,D,S bf16).
// FUSED=0: plain fp32 C-write (un-permuting columns).
template <int FUSED>
__global__ __launch_bounds__(256) void gemm_fused(const unsigned short* __restrict__ A,
                                                  const unsigned short* __restrict__ Bm,
                                                  float* __restrict__ C, int Ndim,
                                                  const float2* __restrict__ rtab,
                                                  const float* __restrict__ nqw,
                                                  const float* __restrict__ nkw,
                                                  unsigned short* __restrict__ Qb,
                                                  unsigned short* __restrict__ Kb,
                                                  unsigned short* __restrict__ Vtb) {
    __shared__ __align__(16) unsigned short As[128 * 64];
    __shared__ __align__(16) unsigned short Bs[128 * 64];
    __shared__ float pse[4][64];
    const int t = threadIdx.x;
    const int bx = blockIdx.x;
    const int m0 = blockIdx.y * 128, n0 = bx * 128;
    const int w = t >> 6, lane = t & 63, quad = lane >> 4, ln = lane & 15;
    const int wm = (w >> 1) * 64;
    const int p = w & 1;
    const int dj0 = p ? 32 : 0;
    // staging lane roles
    const int rl = lane >> 3;             // row within 8-row group
    const int gc = (lane & 7) ^ rl;       // swizzled global chunk this lane fetches
    const int cs = ln & 7;                // read-side swizzle key
    const int woff = (w == 1) ? 32 : (w == 2) ? -32 : 0;   // B-row permutation

    f32x4 acc[4][4];
#pragma unroll
    for (int i = 0; i < 4; ++i)
#pragma unroll
        for (int j = 0; j < 4; ++j) acc[i][j] = (f32x4){0.f, 0.f, 0.f, 0.f};

    const unsigned short* ga = &A[(long long)(m0 + w * 32 + rl) * KDIM + gc * 8];
    const unsigned short* gb = &Bm[(long long)(n0 + w * 32 + woff + rl) * KDIM + gc * 8];

    for (int kt = 0; kt < KDIM / 64; ++kt) {
#pragma unroll
        for (int c = 0; c < 4; ++c) {
            const int r0 = w * 32 + c * 8;
            GLD_LDS16(ga + (long long)(c * 8) * KDIM, &As[r0 * 64]);
            GLD_LDS16(gb + (long long)(c * 8) * KDIM, &Bs[r0 * 64]);
        }
        ga += 64; gb += 64;
        __syncthreads();
#pragma unroll
        for (int ks = 0; ks < 2; ++ks) {
            short8 a[4], b[4];
#pragma unroll
            for (int i = 0; i < 4; ++i) {
                int row = wm + i * 16 + ln;
                a[i] = *(const short8*)&As[row * 64 + (((ks * 4 + quad) ^ cs) << 3)];
            }
#pragma unroll
            for (int j = 0; j < 4; ++j) {
                int row = p * 64 + j * 16 + ln;
                b[j] = *(const short8*)&Bs[row * 64 + (((ks * 4 + quad) ^ cs) << 3)];
            }
#pragma unroll
            for (int i = 0; i < 4; ++i)
#pragma unroll
                for (int j = 0; j < 4; ++j)
                    acc[i][j] = __builtin_amdgcn_mfma_f32_16x16x32_bf16(a[i], b[j], acc[i][j], 0, 0, 0);
        }
        __syncthreads();
    }

    // ---------------- epilogue ----------------
    // fragment (w,j,ln,quad,reg): row = m0+wm+i*16+quad*4+reg, col = n0+dj0+(j&1)*16+(j>>1)*64+ln
    if (!FUSED) {
#pragma unroll
        for (int i = 0; i < 4; ++i)
#pragma unroll
            for (int reg = 0; reg < 4; ++reg) {
                int row = m0 + wm + i * 16 + quad * 4 + reg;
                float* crow = C + (long long)row * Ndim + n0 + ln;
                crow[dj0]      = acc[i][0][reg];
                crow[dj0 + 16] = acc[i][1][reg];
                crow[dj0 + 64] = acc[i][2][reg];
                crow[dj0 + 80] = acc[i][3][reg];
            }
        return;
    }
    const int region = bx / 24;        // 0=Q, 1=K, 2=V (block-uniform)
    const int h = bx % 24;
    if (region < 2) {
        // per-row sum of squares: lane partial over its 4 cols, reduce over 16 lanes,
        // then cross-wave (partner w^1 holds the other 64 cols of the same rows).
#pragma unroll
        for (int i = 0; i < 4; ++i)
#pragma unroll
            for (int reg = 0; reg < 4; ++reg) {
                float s = 0.f;
#pragma unroll
                for (int j = 0; j < 4; ++j) { float v = acc[i][j][reg]; s += v * v; }
#pragma unroll
                for (int off = 8; off; off >>= 1) s += __shfl_xor(s, off, 16);
                if (ln == 0) pse[w][i * 16 + quad * 4 + reg] = s;
            }
        __syncthreads();
        const float* nw = region ? nkw : nqw;
        unsigned short* outp = region ? Kb : Qb;
        const float scl = region ? 1.f : QSCALE;
        const float nw0  = nw[dj0 + ln],      nw1  = nw[dj0 + 16 + ln];
        const float nw64 = nw[dj0 + 64 + ln], nw80 = nw[dj0 + 80 + ln];
#pragma unroll
        for (int i = 0; i < 4; ++i)
#pragma unroll
            for (int reg = 0; reg < 4; ++reg) {
                const int idx = i * 16 + quad * 4 + reg;
                const float tot = pse[w][idx] + pse[w ^ 1][idx];
                const float rr = rsqrtf(tot * (1.f / 128.f) + 1e-6f);
                const int row = m0 + wm + idx;
                const int b = row >> 10, s = row & 1023;
                const long long ob = ((long long)(b * H_ + h) * S_ + s) * HD_;
                {   // pair (j=0, j=2)
                    const int d1 = dj0 + ln;
                    float y1 = acc[i][0][reg] * rr * nw0;
                    float y2 = acc[i][2][reg] * rr * nw64;
                    float2 c1 = rtab[s * HD_ + d1], c2 = rtab[s * HD_ + d1 + 64];
                    outp[ob + d1]      = f2bf((y1 * c1.x - y2 * c1.y) * scl);
                    outp[ob + d1 + 64] = f2bf((y2 * c2.x + y1 * c2.y) * scl);
                }
                {   // pair (j=1, j=3)
                    const int d1 = dj0 + 16 + ln;
                    float y1 = acc[i][1][reg] * rr * nw1;
                    float y2 = acc[i][3][reg] * rr * nw80;
                    float2 c1 = rtab[s * HD_ + d1], c2 = rtab[s * HD_ + d1 + 64];
                    outp[ob + d1]      = f2bf((y1 * c1.x - y2 * c1.y) * scl);
                    outp[ob + d1 + 64] = f2bf((y2 * c2.x + y1 * c2.y) * scl);
                }
            }
    } else {
        // V: no norm/rope; store transposed (B,H,D,S)
#pragma unroll
        for (int i = 0; i < 4; ++i)
#pragma unroll
            for (int reg = 0; reg < 4; ++reg) {
                const int row = m0 + wm + i * 16 + quad * 4 + reg;
                const int b = row >> 10, s = row & 1023;
                const long long vb = (long long)(b * H_ + h) * HD_;
#pragma unroll
                for (int j = 0; j < 4; ++j) {
                    const int d = dj0 + (j & 1) * 16 + (j >> 1) * 64 + ln;
                    Vtb[(vb + d) * S_ + s] = f2bf(acc[i][j][reg]);
                }
            }
    }
}

// ---------------- Flash attention ----------------
// grid (BH=48, S/64=16). 4 waves/block, each wave owns 16 Q rows.
__global__ __launch_bounds__(256) void attn(const unsigned short* __restrict__ Qb,
                                            const unsigned short* __restrict__ Kb,
                                            const unsigned short* __restrict__ Vtb,
                                            unsigned short* __restrict__ Ob) {
    __shared__ __align__(16) unsigned short Ks[64][136];   // 64 keys x 128 d (+8 pad)
    __shared__ __align__(16) unsigned short Vts[128][72];  // 128 d x 64 keys (+8 pad)
    __shared__ __align__(16) unsigned short Ps[4][16][72]; // per-wave P 16x64 (+8 pad)
    const int bh = blockIdx.x, qt = blockIdx.y;
    const int t = threadIdx.x, w = t >> 6, lane = t & 63, quad = lane >> 4, ln = lane & 15;
    const int b = bh / H_, h = bh - b * H_;

    short8 qfrag[4];
    const long long qbase = ((long long)bh * S_ + qt * 64 + w * 16 + ln) * HD_;
#pragma unroll
    for (int ks = 0; ks < 4; ++ks)
        qfrag[ks] = *(const short8*)&Qb[qbase + ks * 32 + quad * 8];

    f32x4 o[8];
#pragma unroll
    for (int n = 0; n < 8; ++n) o[n] = (f32x4){0.f, 0.f, 0.f, 0.f};
    float m_run[4], l_run[4];
#pragma unroll
    for (int r = 0; r < 4; ++r) { m_run[r] = -1e30f; l_run[r] = 0.f; }

    for (int kt = 0; kt < S_ / 64; ++kt) {
        __syncthreads();
#pragma unroll
        for (int c = 0; c < 4; ++c) {
            int i = c * 256 + t;
            int r = i >> 4, cg = (i & 15) << 3;
            *(uint4*)&Ks[r][cg] = *(const uint4*)&Kb[((long long)bh * S_ + kt * 64 + r) * HD_ + cg];
            int r2 = i >> 3, cg2 = (i & 7) << 3;
            *(uint4*)&Vts[r2][cg2] = *(const uint4*)&Vtb[((long long)bh * HD_ + r2) * S_ + kt * 64 + cg2];
        }
        __syncthreads();
        // S = Q K^T  (4 subtiles of 16 keys)
        f32x4 sj[4];
#pragma unroll
        for (int j = 0; j < 4; ++j) {
            f32x4 sa = (f32x4){0.f, 0.f, 0.f, 0.f};
#pragma unroll
            for (int ks = 0; ks < 4; ++ks) {
                short8 bb = *(const short8*)&Ks[j * 16 + ln][ks * 32 + quad * 8];
                sa = __builtin_amdgcn_mfma_f32_16x16x32_bf16(qfrag[ks], bb, sa, 0, 0, 0);
            }
            sj[j] = sa;
        }
        // online softmax: rows live in a quad (row = quad*4+reg, cols across 16 lanes)
        float al[4];
#pragma unroll
        for (int r = 0; r < 4; ++r) {
            float m = fmaxf(fmaxf(sj[0][r], sj[1][r]), fmaxf(sj[2][r], sj[3][r]));
#pragma unroll
            for (int off = 8; off; off >>= 1) m = fmaxf(m, __shfl_xor(m, off, 16));
            float mn = fmaxf(m_run[r], m);
            al[r] = __expf(m_run[r] - mn);
            m_run[r] = mn;
            float sum = 0.f;
#pragma unroll
            for (int j = 0; j < 4; ++j) {
                float p = __expf(sj[j][r] - mn);
                sj[j][r] = p;
                sum += p;
            }
#pragma unroll
            for (int off = 8; off; off >>= 1) sum += __shfl_xor(sum, off, 16);
            l_run[r] = l_run[r] * al[r] + sum;
        }
#pragma unroll
        for (int n = 0; n < 8; ++n)
#pragma unroll
            for (int r = 0; r < 4; ++r) o[n][r] *= al[r];
        // P: C-layout -> LDS -> A-layout
#pragma unroll
        for (int j = 0; j < 4; ++j)
#pragma unroll
            for (int r = 0; r < 4; ++r)
                Ps[w][quad * 4 + r][j * 16 + ln] = f2bf(sj[j][r]);
        __asm__ volatile("s_waitcnt lgkmcnt(0)" ::: "memory");
        // O += P V
#pragma unroll
        for (int ks = 0; ks < 2; ++ks) {
            short8 pf = *(const short8*)&Ps[w][ln][ks * 32 + quad * 8];
#pragma unroll
            for (int n = 0; n < 8; ++n) {
                short8 vf = *(const short8*)&Vts[n * 16 + ln][ks * 32 + quad * 8];
                o[n] = __builtin_amdgcn_mfma_f32_16x16x32_bf16(pf, vf, o[n], 0, 0, 0);
            }
        }
    }
    float inv[4];
#pragma unroll
    for (int r = 0; r < 4; ++r) inv[r] = 1.f / l_run[r];
    const int row_s = qt * 64 + w * 16 + quad * 4;
#pragma unroll
    for (int n = 0; n < 8; ++n)
#pragma unroll
        for (int r = 0; r < 4; ++r) {
            long long off = ((long long)b * S_ + row_s + r) * DM_ + h * HD_ + n * 16 + ln;
            Ob[off] = f2bf(o[n][r] * inv[r]);
        }
}

// ---------------- host side ----------------
extern "C" void kernel_launch(void* const* d_in, const int* in_sizes, int n_in,
                              void* d_out, int out_size, void* d_ws, size_t ws_size,
                              hipStream_t stream) {
    const float* hs    = (const float*)d_in[0];
    const float* freqs = (const float*)d_in[1];
    const float* Wq    = (const float*)d_in[2];
    const float* Wk    = (const float*)d_in[3];
    const float* Wv    = (const float*)d_in[4];
    const float* Wo    = (const float*)d_in[5];
    const float* Wo_   = (const float*)d_in[5];
    const float* nqw   = (const float*)d_in[6];
    const float* nkw   = (const float*)d_in[7];
    float* out = (float*)d_out;
    (void)Wo_;

    char* ws = (char*)d_ws;
    // workspace layout (bytes)
    unsigned short* Xb    = (unsigned short*)(ws);                   // 12,582,912
    unsigned short* Wqkvb = (unsigned short*)(ws + 12582912LL);      // 56,623,104 (Wq|Wk|Wv)
    unsigned short* Wob   = (unsigned short*)(ws + 69206016LL);      // 18,874,368
    unsigned short* Qb    = (unsigned short*)(ws + 88080384LL);      // 12,582,912 (B,H,S,D)
    unsigned short* Kb    = (unsigned short*)(ws + 100663296LL);     // 12,582,912 (B,H,S,D)
    unsigned short* Vtb   = (unsigned short*)(ws + 113246208LL);     // 12,582,912 (B,H,D,S)
    unsigned short* Ob    = (unsigned short*)(ws + 125829120LL);     // 12,582,912 (B,S,H*D)
    float2*         rtab  = (float2*)        (ws + 138412032LL);     // 1,048,576
    // total: 139,460,608 bytes

    // 1. convert inputs to bf16 + rope table
    cvt_bf16<<<6144, 256, 0, stream>>>(hs, Xb, 1572864);
    cvt_bf16<<<9216, 256, 0, stream>>>(Wq, Wqkvb,            2359296);
    cvt_bf16<<<9216, 256, 0, stream>>>(Wk, Wqkvb +  9437184, 2359296);
    cvt_bf16<<<9216, 256, 0, stream>>>(Wv, Wqkvb + 18874368, 2359296);
    cvt_bf16<<<9216, 256, 0, stream>>>(Wo, Wob,              2359296);
    rope_tab<<<512, 256, 0, stream>>>(freqs, rtab);
    // 2. fused QKV projection + RMSNorm + RoPE + layout
    gemm_fused<1><<<dim3(72, 16), 256, 0, stream>>>(Xb, Wqkvb, nullptr, 0,
                                                    rtab, nqw, nkw, Qb, Kb, Vtb);
    // 3. flash attention
    attn<<<dim3(BH_, S_ / 64), 256, 0, stream>>>(Qb, Kb, Vtb, Ob);
    // 4. output projection -> d_out fp32
    gemm_fused<0><<<dim3(24, 16), 256, 0, stream>>>(Ob, Wob, out, DM_,
                                                    nullptr, nullptr, nullptr,
                                                    nullptr, nullptr, nullptr);
}

// Round 4
// 454.399 us; speedup vs baseline: 1.2510x; 1.1191x over previous
//
#include <hip/hip_runtime.h>
#include <hip/hip_bf16.h>
#include <math.h>

// Problem: B=2, S=1024, D_MODEL=3072, HEADS=24, HEAD_DIM=128
#define B_   2
#define S_   1024
#define DM_  3072
#define H_   24
#define HD_  128
#define BH_  (B_*H_)          // 48
#define KDIM 3072             // K of both GEMMs
#define QSCALE 0.08838834764831845f   // 1/sqrt(128)

typedef __attribute__((ext_vector_type(8))) short short8;
typedef __attribute__((ext_vector_type(4))) float f32x4;

__device__ __forceinline__ unsigned short f2bf(float f) {
    union { float f; unsigned u; } v; v.f = f;
    unsigned r = v.u + 0x7fffu + ((v.u >> 16) & 1u);   // RNE
    return (unsigned short)(r >> 16);
}

// async 16B global -> LDS (wave-uniform lds base; HW scatters lane*16)
#define GLD_LDS16(gptr, ldsptr)                                                            \
    __builtin_amdgcn_global_load_lds(                                                      \
        (const __attribute__((address_space(1))) unsigned int*)(gptr),                     \
        (__attribute__((address_space(3))) unsigned int*)(ldsptr), 16, 0, 0)

// ---------------- merged fp32->bf16 conversion + rope table ----------------
// segments (in float4 units): hs(1572864) | Wq | Wk | Wv (2359296 ea) | Wo | rope(32768)
#define SEG0 1572864
#define SEGW 2359296
#define SB1  (SEG0 + SEGW)        // 3932160
#define SB2  (SB1 + SEGW)         // 6291456
#define SB3  (SB2 + SEGW)         // 8650752
#define SB4  (SB3 + SEGW)         // 11010048
#define SB5  (SB4 + 32768)        // 11042816
#define CVT_BLOCKS 43136          // SB5/256

__global__ __launch_bounds__(256) void cvt_all(const float* __restrict__ hs,
                                               const float* __restrict__ Wq,
                                               const float* __restrict__ Wk,
                                               const float* __restrict__ Wv,
                                               const float* __restrict__ Wo,
                                               const float* __restrict__ freqs,
                                               unsigned short* __restrict__ Xb,
                                               unsigned short* __restrict__ Wqkvb,
                                               unsigned short* __restrict__ Wob,
                                               float2* __restrict__ tab) {
    int i = blockIdx.x * 256 + threadIdx.x;
    const float* src;
    unsigned short* dst;
    int j;
    if (i < SEG0)      { src = hs; dst = Xb;              j = i; }
    else if (i < SB1)  { src = Wq; dst = Wqkvb;           j = i - SEG0; }
    else if (i < SB2)  { src = Wk; dst = Wqkvb + 9437184; j = i - SB1; }
    else if (i < SB3)  { src = Wv; dst = Wqkvb + 18874368; j = i - SB2; }
    else if (i < SB4)  { src = Wo; dst = Wob;             j = i - SB3; }
    else {
        j = i - SB4;               // rope: 32768 float4 of freqs
        float4 f = ((const float4*)freqs)[j];
        float4 lo = make_float4(cosf(f.x), sinf(f.x), cosf(f.y), sinf(f.y));
        float4 hi = make_float4(cosf(f.z), sinf(f.z), cosf(f.w), sinf(f.w));
        ((float4*)tab)[2 * j]     = lo;
        ((float4*)tab)[2 * j + 1] = hi;
        return;
    }
    float4 v = ((const float4*)src)[j];
    ushort4 o;
    o.x = f2bf(v.x); o.y = f2bf(v.y); o.z = f2bf(v.z); o.w = f2bf(v.w);
    ((ushort4*)dst)[j] = o;
}

// ---------------- GEMM: C[M,N] = A[M,K] * B[N,K]^T  (bf16 in) ----------------
// 128x128 tile, BK=64, 256 threads (4 waves, 64x64 each), 16x16x32 bf16 MFMA.
// Staging via global_load_lds width=16 with XOR chunk swizzle (conflict-free).
// B rows are PERMUTED at staging so that wave p=w&1 holds global cols
//   p=0: {0-31, 64-95}, p=1: {32-63, 96-127}
// -> each RoPE pair (d, d+64) lives in one lane (j and j+2).
// FUSED=1: N=9216 QKV projection; epilogue does RMSNorm+RoPE and writes
//   Qb,Kb (B,H,S,D bf16; Q pre-scaled 1/sqrt(128)) and Vtb (B,H,D,S bf16).
// FUSED=0: plain fp32 C-write (un-permuting columns).
template <int FUSED>
__global__ __launch_bounds__(256) void gemm_fused(const unsigned short* __restrict__ A,
                                                  const unsigned short* __restrict__ Bm,
                                                  float* __restrict__ C, int Ndim,
                                                  const float2* __restrict__ rtab,
                                                  const float* __restrict__ nqw,
                                                  const float* __restrict__ nkw,
                                                  unsigned short* __restrict__ Qb,
                                                  unsigned short* __restrict__ Kb,
                                                  unsigned short* __restrict__ Vtb) {
    __shared__ __align__(16) unsigned short As[128 * 64];
    __shared__ __align__(16) unsigned short Bs[128 * 64];
    __shared__ float pse[4][64];
    const int t = threadIdx.x;
    const int bx = blockIdx.x;
    const int m0 = blockIdx.y * 128, n0 = bx * 128;
    const int w = t >> 6, lane = t & 63, quad = lane >> 4, ln = lane & 15;
    const int wm = (w >> 1) * 64;
    const int p = w & 1;
    const int dj0 = p ? 32 : 0;
    const int rl = lane >> 3;             // row within 8-row staging group
    const int gc = (lane & 7) ^ rl;       // swizzled global chunk this lane fetches
    const int cs = ln & 7;                // read-side swizzle key
    const int woff = (w == 1) ? 32 : (w == 2) ? -32 : 0;   // B-row permutation

    f32x4 acc[4][4];
#pragma unroll
    for (int i = 0; i < 4; ++i)
#pragma unroll
        for (int j = 0; j < 4; ++j) acc[i][j] = (f32x4){0.f, 0.f, 0.f, 0.f};

    const unsigned short* ga = &A[(long long)(m0 + w * 32 + rl) * KDIM + gc * 8];
    const unsigned short* gb = &Bm[(long long)(n0 + w * 32 + woff + rl) * KDIM + gc * 8];

    for (int kt = 0; kt < KDIM / 64; ++kt) {
#pragma unroll
        for (int c = 0; c < 4; ++c) {
            const int r0 = w * 32 + c * 8;
            GLD_LDS16(ga + (long long)(c * 8) * KDIM, &As[r0 * 64]);
            GLD_LDS16(gb + (long long)(c * 8) * KDIM, &Bs[r0 * 64]);
        }
        ga += 64; gb += 64;
        __syncthreads();
#pragma unroll
        for (int ks = 0; ks < 2; ++ks) {
            short8 a[4], b[4];
#pragma unroll
            for (int i = 0; i < 4; ++i) {
                int row = wm + i * 16 + ln;
                a[i] = *(const short8*)&As[row * 64 + (((ks * 4 + quad) ^ cs) << 3)];
            }
#pragma unroll
            for (int j = 0; j < 4; ++j) {
                int row = p * 64 + j * 16 + ln;
                b[j] = *(const short8*)&Bs[row * 64 + (((ks * 4 + quad) ^ cs) << 3)];
            }
#pragma unroll
            for (int i = 0; i < 4; ++i)
#pragma unroll
                for (int j = 0; j < 4; ++j)
                    acc[i][j] = __builtin_amdgcn_mfma_f32_16x16x32_bf16(a[i], b[j], acc[i][j], 0, 0, 0);
        }
        __syncthreads();
    }

    // epilogue: row = m0+wm+i*16+quad*4+reg, col = n0+dj0+(j&1)*16+(j>>1)*64+ln
    if (!FUSED) {
#pragma unroll
        for (int i = 0; i < 4; ++i)
#pragma unroll
            for (int reg = 0; reg < 4; ++reg) {
                int row = m0 + wm + i * 16 + quad * 4 + reg;
                float* crow = C + (long long)row * Ndim + n0 + ln;
                crow[dj0]      = acc[i][0][reg];
                crow[dj0 + 16] = acc[i][1][reg];
                crow[dj0 + 64] = acc[i][2][reg];
                crow[dj0 + 80] = acc[i][3][reg];
            }
        return;
    }
    const int region = bx / 24;        // 0=Q, 1=K, 2=V (block-uniform)
    const int h = bx % 24;
    if (region < 2) {
#pragma unroll
        for (int i = 0; i < 4; ++i)
#pragma unroll
            for (int reg = 0; reg < 4; ++reg) {
                float s = 0.f;
#pragma unroll
                for (int j = 0; j < 4; ++j) { float v = acc[i][j][reg]; s += v * v; }
#pragma unroll
                for (int off = 8; off; off >>= 1) s += __shfl_xor(s, off, 16);
                if (ln == 0) pse[w][i * 16 + quad * 4 + reg] = s;
            }
        __syncthreads();
        const float* nw = region ? nkw : nqw;
        unsigned short* outp = region ? Kb : Qb;
        const float scl = region ? 1.f : QSCALE;
        const float nw0  = nw[dj0 + ln],      nw1  = nw[dj0 + 16 + ln];
        const float nw64 = nw[dj0 + 64 + ln], nw80 = nw[dj0 + 80 + ln];
#pragma unroll
        for (int i = 0; i < 4; ++i)
#pragma unroll
            for (int reg = 0; reg < 4; ++reg) {
                const int idx = i * 16 + quad * 4 + reg;
                const float tot = pse[w][idx] + pse[w ^ 1][idx];
                const float rr = rsqrtf(tot * (1.f / 128.f) + 1e-6f);
                const int row = m0 + wm + idx;
                const int b = row >> 10, s = row & 1023;
                const long long ob = ((long long)(b * H_ + h) * S_ + s) * HD_;
                {
                    const int d1 = dj0 + ln;
                    float y1 = acc[i][0][reg] * rr * nw0;
                    float y2 = acc[i][2][reg] * rr * nw64;
                    float2 c1 = rtab[s * HD_ + d1], c2 = rtab[s * HD_ + d1 + 64];
                    outp[ob + d1]      = f2bf((y1 * c1.x - y2 * c1.y) * scl);
                    outp[ob + d1 + 64] = f2bf((y2 * c2.x + y1 * c2.y) * scl);
                }
                {
                    const int d1 = dj0 + 16 + ln;
                    float y1 = acc[i][1][reg] * rr * nw1;
                    float y2 = acc[i][3][reg] * rr * nw80;
                    float2 c1 = rtab[s * HD_ + d1], c2 = rtab[s * HD_ + d1 + 64];
                    outp[ob + d1]      = f2bf((y1 * c1.x - y2 * c1.y) * scl);
                    outp[ob + d1 + 64] = f2bf((y2 * c2.x + y1 * c2.y) * scl);
                }
            }
    } else {
        // V: store transposed (B,H,D,S)
#pragma unroll
        for (int i = 0; i < 4; ++i)
#pragma unroll
            for (int reg = 0; reg < 4; ++reg) {
                const int row = m0 + wm + i * 16 + quad * 4 + reg;
                const int b = row >> 10, s = row & 1023;
                const long long vb = (long long)(b * H_ + h) * HD_;
#pragma unroll
                for (int j = 0; j < 4; ++j) {
                    const int d = dj0 + (j & 1) * 16 + (j >> 1) * 64 + ln;
                    Vtb[(vb + d) * S_ + s] = f2bf(acc[i][j][reg]);
                }
            }
    }
}

// ---------------- Flash attention (no-max softmax; scores bounded by ~11.32)
// grid (BH=48, S/64=16). 4 waves/block, each wave owns 16 Q rows.
// K/V staged via global_load_lds with XOR chunk swizzle.
__global__ __launch_bounds__(256) void attn(const unsigned short* __restrict__ Qb,
                                            const unsigned short* __restrict__ Kb,
                                            const unsigned short* __restrict__ Vtb,
                                            unsigned short* __restrict__ Ob) {
    __shared__ __align__(16) unsigned short Ks[64 * 128];   // swizzled: slot s of row r = chunk s^(r&15)
    __shared__ __align__(16) unsigned short Vts[128 * 64];  // swizzled: slot s of row r = chunk s^(r&7)
    __shared__ __align__(16) unsigned short Ps[4][16][72];  // per-wave P 16x64 (+8 pad)
    const int bh = blockIdx.x, qt = blockIdx.y;
    const int t = threadIdx.x, w = t >> 6, lane = t & 63, quad = lane >> 4, ln = lane & 15;
    const int b = bh / H_, h = bh - b * H_;

    short8 qfrag[4];
    const long long qbase = ((long long)bh * S_ + qt * 64 + w * 16 + ln) * HD_;
#pragma unroll
    for (int ks = 0; ks < 4; ++ks)
        qfrag[ks] = *(const short8*)&Qb[qbase + ks * 32 + quad * 8];

    f32x4 o[8];
#pragma unroll
    for (int n = 0; n < 8; ++n) o[n] = (f32x4){0.f, 0.f, 0.f, 0.f};
    float l_run[4] = {0.f, 0.f, 0.f, 0.f};

    // staging lane roles (K: 4 rows/wave-inst of 16 chunks; V: 8 rows of 8 chunks)
    const int krow_l = lane >> 4, ksl = lane & 15;        // K: sub-row, slot
    const int vrow_l = lane >> 3, vsl = lane & 7;         // V: sub-row, slot

    for (int kt = 0; kt < S_ / 64; ++kt) {
        __syncthreads();
#pragma unroll
        for (int c = 0; c < 4; ++c) {
            {   // K tile: rows c*16+w*4 .. +3
                const int r = c * 16 + w * 4 + krow_l;
                const int gcn = ksl ^ (r & 15);
                GLD_LDS16(&Kb[((long long)bh * S_ + kt * 64 + r) * HD_ + gcn * 8],
                          &Ks[(c * 16 + w * 4) * 128]);
            }
            {   // V tile: rows c*32+w*8 .. +7  (row = d, cols = 64 keys)
                const int r = c * 32 + w * 8 + vrow_l;
                const int gcn = vsl ^ (r & 7);
                GLD_LDS16(&Vtb[((long long)bh * HD_ + r) * S_ + kt * 64 + gcn * 8],
                          &Vts[(c * 32 + w * 8) * 64]);
            }
        }
        __syncthreads();
        // S = Q K^T  (4 subtiles of 16 keys)
        f32x4 sj[4];
#pragma unroll
        for (int j = 0; j < 4; ++j) {
            f32x4 sa = (f32x4){0.f, 0.f, 0.f, 0.f};
#pragma unroll
            for (int ks = 0; ks < 4; ++ks) {
                const int row = j * 16 + ln;
                const int slot = (ks * 4 + quad) ^ (row & 15);
                short8 bb = *(const short8*)&Ks[row * 128 + slot * 8];
                sa = __builtin_amdgcn_mfma_f32_16x16x32_bf16(qfrag[ks], bb, sa, 0, 0, 0);
            }
            sj[j] = sa;
        }
        // softmax without max-subtraction (scores bounded); accumulate l
#pragma unroll
        for (int r = 0; r < 4; ++r) {
            float sum = 0.f;
#pragma unroll
            for (int j = 0; j < 4; ++j) {
                float p = __expf(sj[j][r]);
                sj[j][r] = p;
                sum += p;
            }
#pragma unroll
            for (int off = 8; off; off >>= 1) sum += __shfl_xor(sum, off, 16);
            l_run[r] += sum;
        }
        // P: C-layout -> LDS -> A-layout
#pragma unroll
        for (int j = 0; j < 4; ++j)
#pragma unroll
            for (int r = 0; r < 4; ++r)
                Ps[w][quad * 4 + r][j * 16 + ln] = f2bf(sj[j][r]);
        __asm__ volatile("s_waitcnt lgkmcnt(0)" ::: "memory");
        // O += P V
#pragma unroll
        for (int ks = 0; ks < 2; ++ks) {
            short8 pf = *(const short8*)&Ps[w][ln][ks * 32 + quad * 8];
#pragma unroll
            for (int n = 0; n < 8; ++n) {
                const int row = n * 16 + ln;
                const int slot = (ks * 4 + quad) ^ (row & 7);
                short8 vf = *(const short8*)&Vts[row * 64 + slot * 8];
                o[n] = __builtin_amdgcn_mfma_f32_16x16x32_bf16(pf, vf, o[n], 0, 0, 0);
            }
        }
    }
    float inv[4];
#pragma unroll
    for (int r = 0; r < 4; ++r) inv[r] = 1.f / l_run[r];
    const int row_s = qt * 64 + w * 16 + quad * 4;
#pragma unroll
    for (int n = 0; n < 8; ++n)
#pragma unroll
        for (int r = 0; r < 4; ++r) {
            long long off = ((long long)b * S_ + row_s + r) * DM_ + h * HD_ + n * 16 + ln;
            Ob[off] = f2bf(o[n][r] * inv[r]);
        }
}

// ---------------- host side ----------------
extern "C" void kernel_launch(void* const* d_in, const int* in_sizes, int n_in,
                              void* d_out, int out_size, void* d_ws, size_t ws_size,
                              hipStream_t stream) {
    const float* hs    = (const float*)d_in[0];
    const float* freqs = (const float*)d_in[1];
    const float* Wq    = (const float*)d_in[2];
    const float* Wk    = (const float*)d_in[3];
    const float* Wv    = (const float*)d_in[4];
    const float* Wo    = (const float*)d_in[5];
    const float* nqw   = (const float*)d_in[6];
    const float* nkw   = (const float*)d_in[7];
    float* out = (float*)d_out;

    char* ws = (char*)d_ws;
    unsigned short* Xb    = (unsigned short*)(ws);                   // 12,582,912
    unsigned short* Wqkvb = (unsigned short*)(ws + 12582912LL);      // 56,623,104 (Wq|Wk|Wv)
    unsigned short* Wob   = (unsigned short*)(ws + 69206016LL);      // 18,874,368
    unsigned short* Qb    = (unsigned short*)(ws + 88080384LL);      // 12,582,912 (B,H,S,D)
    unsigned short* Kb    = (unsigned short*)(ws + 100663296LL);     // 12,582,912 (B,H,S,D)
    unsigned short* Vtb   = (unsigned short*)(ws + 113246208LL);     // 12,582,912 (B,H,D,S)
    unsigned short* Ob    = (unsigned short*)(ws + 125829120LL);     // 12,582,912 (B,S,H*D)
    float2*         rtab  = (float2*)        (ws + 138412032LL);     // 1,048,576
    // total: 139,460,608 bytes

    // 1. all conversions + rope table in one launch
    cvt_all<<<CVT_BLOCKS, 256, 0, stream>>>(hs, Wq, Wk, Wv, Wo, freqs,
                                            Xb, Wqkvb, Wob, rtab);
    // 2. fused QKV projection + RMSNorm + RoPE + layout
    gemm_fused<1><<<dim3(72, 16), 256, 0, stream>>>(Xb, Wqkvb, nullptr, 0,
                                                    rtab, nqw, nkw, Qb, Kb, Vtb);
    // 3. flash attention
    attn<<<dim3(BH_, S_ / 64), 256, 0, stream>>>(Qb, Kb, Vtb, Ob);
    // 4. output projection -> d_out fp32
    gemm_fused<0><<<dim3(24, 16), 256, 0, stream>>>(Ob, Wob, out, DM_,
                                                    nullptr, nullptr, nullptr,
                                                    nullptr, nullptr, nullptr);
}